// Round 4
// baseline (1117.519 us; speedup 1.0000x reference)
//
#include <hip/hip_runtime.h>

#define B_ 64
#define S_ 2048
#define D_ 64
#define H_ 128
#define G_ 512
#define CH 16

typedef float f32x4 __attribute__((ext_vector_type(4)));
typedef short bf16x8 __attribute__((ext_vector_type(8)));

#define MFMA16(a, b, c) __builtin_amdgcn_mfma_f32_16x16x32_bf16((a), (b), (c), 0, 0, 0)
#define RCPF(x) __builtin_amdgcn_rcpf(x)
#define LOG2E 1.442695041f

// light per-step barrier: drain LDS only (keep global x-prefetch in flight)
#define STEP_SYNC() do {                                  \
    __builtin_amdgcn_sched_barrier(0);                    \
    asm volatile("s_waitcnt lgkmcnt(0)" ::: "memory");    \
    __builtin_amdgcn_s_barrier();                         \
    __builtin_amdgcn_sched_barrier(0);                    \
} while (0)

__device__ __forceinline__ short f2bf(float f) {
    unsigned u = __builtin_bit_cast(unsigned, f);
    return (short)((u + 0x7FFFu + ((u >> 16) & 1u)) >> 16);  // RNE
}
__device__ __forceinline__ float bflo(unsigned u) { return __builtin_bit_cast(float, u << 16); }
__device__ __forceinline__ float bfhi(unsigned u) { return __builtin_bit_cast(float, u & 0xFFFF0000u); }
__device__ __forceinline__ float sigm_f(float x) { return RCPF(1.0f + __expf(-x)); }

// One block per batch element; 512 threads = 8 waves.
// Wave w owns hidden units [16w,16w+16). Gate-split across l4 (i,f,g,o):
// lane (l4,l15) computes only gate l4 for unit l15 via the unified chain
//   t = a*rcp(1+exp2(m*z)) + b ; gates rejoin in group 0 via 3 parallel shfl.
__launch_bounds__(512, 2)
__global__ void lstm_fused(const float* __restrict__ x, const float* __restrict__ Wx,
                           const float* __restrict__ Wh, const float* __restrict__ bias,
                           const float* __restrict__ Wd, const float* __restrict__ bd,
                           float* __restrict__ out) {
    const int tid = threadIdx.x;
    const int lane = tid & 63;
    const int wid = tid >> 6;      // 0..7
    const int l15 = lane & 15;
    const int l4 = lane >> 4;      // 0..3 == gate (i,f,g,o)
    const int bb = blockIdx.x;

    __shared__ alignas(16) short hist[CH][H_];   // h ring (bf16), slot = t & 15
    __shared__ alignas(16) short xbf[CH][72];    // x chunk (padded)
    __shared__ alignas(16) float xzc[CH][G_];    // layout: [tm][unit*4 + gate]

    ((unsigned*)hist)[tid] = 0u;
    ((unsigned*)hist)[tid + 512] = 0u;

    const int col0 = wid * 16 + l15;             // hidden unit
    const bool b0 = (l4 & 1) != 0;
    const bool b1 = (l4 & 2) != 0;

    // --- Wh B-fragments, col = ct*128 + col0, k = kt*32 + l4*8 + e ---
    bf16x8 bh[4][4];
#pragma unroll
    for (int ct = 0; ct < 4; ++ct) {
        const int col = ct * H_ + col0;
#pragma unroll
        for (int kt = 0; kt < 4; ++kt) {
            bf16x8 v;
#pragma unroll
            for (int e = 0; e < 8; ++e)
                v[e] = f2bf(Wh[(kt * 32 + l4 * 8 + e) * G_ + col]);
            bh[ct][kt] = v;
        }
    }
    // --- Wx B-fragments ---
    bf16x8 bx[4][2];
#pragma unroll
    for (int ct = 0; ct < 4; ++ct) {
        const int col = ct * H_ + col0;
#pragma unroll
        for (int kt = 0; kt < 2; ++kt) {
            bf16x8 v;
#pragma unroll
            for (int e = 0; e < 8; ++e)
                v[e] = f2bf(Wx[(kt * 32 + l4 * 8 + e) * G_ + col]);
            bx[ct][kt] = v;
        }
    }

    float bvr[4];
#pragma unroll
    for (int ct = 0; ct < 4; ++ct) bvr[ct] = bias[ct * H_ + col0];
    const float wd0 = Wd[lane * 2 + 0];
    const float wd1 = Wd[lane * 2 + 1];
    const float bdv = bd[0];
    float c_reg = 0.0f;                          // valid in lanes 0..15 only

    // per-lane unified gate coefficients: t = a*rcp(1+exp2(m*z)) + b
    const float m_c = (l4 == 2) ? (-2.0f * LOG2E) : (-LOG2E);
    const float a_c = (l4 == 2) ? 2.0f : 1.0f;
    const float b_c = (l4 == 2) ? -1.0f : 0.0f;

    const float* xb = x + (size_t)bb * S_ * D_;
    float* ob = out + (size_t)bb * S_;

    float xp0 = xb[tid * 2 + 0];
    float xp1 = xb[tid * 2 + 1];

    // persistent accumulator chains: only reg 0 is meaningful (rows 1-3 stale)
    f32x4 acc0 = {0.f, 0.f, 0.f, 0.f}, acc1 = acc0, acc2 = acc0, acc3 = acc0;

    for (int tc = 0; tc < S_; tc += CH) {
        // commit prefetched x chunk
        xbf[tid >> 5][(tid & 31) * 2 + 0] = f2bf(xp0);
        xbf[tid >> 5][(tid & 31) * 2 + 1] = f2bf(xp1);
        __syncthreads();
        if (tc + CH < S_) {
            xp0 = xb[(tc + CH) * D_ + tid * 2 + 0];
            xp1 = xb[(tc + CH) * D_ + tid * 2 + 1];
        }
        // xz_chunk = X[16x64] @ Wx + b -> layout [tm][unit*4+gate]
#pragma unroll
        for (int ct = 0; ct < 4; ++ct) {
            f32x4 cacc = {bvr[ct], bvr[ct], bvr[ct], bvr[ct]};
#pragma unroll
            for (int kt = 0; kt < 2; ++kt) {
                const bf16x8 a = *reinterpret_cast<const bf16x8*>(&xbf[l15][kt * 32 + l4 * 8]);
                cacc = MFMA16(a, bx[ct][kt], cacc);
            }
#pragma unroll
            for (int r = 0; r < 4; ++r)
                xzc[l4 * 4 + r][col0 * 4 + ct] = cacc[r];   // D row = (lane>>4)*4+r [m89]
        }
        // dense head for the PREVIOUS chunk (hist = h_{tc-16..tc-1})
        if (tc > 0) {
#pragma unroll
            for (int s = 0; s < 2; ++s) {
                const int row = wid * 2 + s;
                const unsigned hp = *reinterpret_cast<const unsigned*>(&hist[row][lane * 2]);
                float p = bflo(hp) * wd0 + bfhi(hp) * wd1;
                p += __shfl_xor(p, 1);  p += __shfl_xor(p, 2);  p += __shfl_xor(p, 4);
                p += __shfl_xor(p, 8);  p += __shfl_xor(p, 16); p += __shfl_xor(p, 32);
                if (lane == 0) ob[tc - CH + row] = sigm_f(p + bdv);
            }
        }
        __syncthreads();   // xzc ready; hist fully consumed before overwrite

#pragma unroll
        for (int tm = 0; tm < CH; ++tm) {
            const int prev = (tm + CH - 1) & (CH - 1);
            const short* hsrc = hist[prev];
            const bf16x8 a0 = *reinterpret_cast<const bf16x8*>(&hsrc[ 0 + l4 * 8]);
            const bf16x8 a1 = *reinterpret_cast<const bf16x8*>(&hsrc[32 + l4 * 8]);
            const bf16x8 a2 = *reinterpret_cast<const bf16x8*>(&hsrc[64 + l4 * 8]);
            const bf16x8 a3 = *reinterpret_cast<const bf16x8*>(&hsrc[96 + l4 * 8]);
            // this lane's 4 gate pre-activations (i,f,g,o for unit col0), one b128
            const f32x4 xzq = *reinterpret_cast<const f32x4*>(&xzc[tm][col0 * 4]);

            // init only reg 0 of each chain (row l4*4 is the only row read)
            acc0[0] = xzq[0];  acc1[0] = xzq[1];  acc2[0] = xzq[2];  acc3[0] = xzq[3];

            acc0 = MFMA16(a0, bh[0][0], acc0);
            acc1 = MFMA16(a0, bh[1][0], acc1);
            acc2 = MFMA16(a0, bh[2][0], acc2);
            acc3 = MFMA16(a0, bh[3][0], acc3);
            acc0 = MFMA16(a1, bh[0][1], acc0);
            acc1 = MFMA16(a1, bh[1][1], acc1);
            acc2 = MFMA16(a1, bh[2][1], acc2);
            acc3 = MFMA16(a1, bh[3][1], acc3);
            acc0 = MFMA16(a2, bh[0][2], acc0);
            acc1 = MFMA16(a2, bh[1][2], acc1);
            acc2 = MFMA16(a2, bh[2][2], acc2);
            acc3 = MFMA16(a2, bh[3][2], acc3);
            acc0 = MFMA16(a3, bh[0][3], acc0);
            acc1 = MFMA16(a3, bh[1][3], acc1);
            acc2 = MFMA16(a3, bh[2][3], acc2);
            acc3 = MFMA16(a3, bh[3][3], acc3);

            // lane's gate z = full pre-activation (xz folded in via C-init)
            const float zsel = b1 ? (b0 ? acc3[0] : acc2[0]) : (b0 ? acc1[0] : acc0[0]);

            // unified gate activation (2 transcendentals)
            const float t = a_c * RCPF(1.0f + __expf(zsel * m_c * 0.693147181f)) + b_c;

            // rejoin: group 0 receives f,g,o via 3 independent shfl
            const float rf = __shfl_xor(t, 16);
            const float rg = __shfl_xor(t, 32);
            const float ro = __shfl_xor(t, 48);

            if (lane < 16) {
                c_reg = rf * c_reg + t * rg;     // f*c + i*g
                const float th = 2.0f * RCPF(1.0f + __expf(-2.0f * c_reg)) - 1.0f;
                const float hv = ro * th;
                hist[tm][col0] = f2bf(hv);
            }
            STEP_SYNC();   // h_t visible to all waves for step t+1
        }
    }

    // dense head for the final 16 steps
#pragma unroll
    for (int s = 0; s < 2; ++s) {
        const int row = wid * 2 + s;
        const unsigned hp = *reinterpret_cast<const unsigned*>(&hist[row][lane * 2]);
        float p = bflo(hp) * wd0 + bfhi(hp) * wd1;
        p += __shfl_xor(p, 1);  p += __shfl_xor(p, 2);  p += __shfl_xor(p, 4);
        p += __shfl_xor(p, 8);  p += __shfl_xor(p, 16); p += __shfl_xor(p, 32);
        if (lane == 0) ob[S_ - CH + row] = sigm_f(p + bdv);
    }
}

extern "C" void kernel_launch(void* const* d_in, const int* in_sizes, int n_in,
                              void* d_out, int out_size, void* d_ws, size_t ws_size,
                              hipStream_t stream) {
    const float* x  = (const float*)d_in[0];
    const float* Wx = (const float*)d_in[1];
    const float* Wh = (const float*)d_in[2];
    const float* b  = (const float*)d_in[3];
    const float* Wd = (const float*)d_in[4];
    const float* bd = (const float*)d_in[5];
    float* out = (float*)d_out;

    lstm_fused<<<B_, 512, 0, stream>>>(x, Wx, Wh, b, Wd, bd, out);
}

// Round 7
// 1087.643 us; speedup vs baseline: 1.0275x; 1.0275x over previous
//
#include <hip/hip_runtime.h>

#define B_ 64
#define S_ 2048
#define D_ 64
#define H_ 128
#define G_ 512
#define CH 16

typedef float f32x4 __attribute__((ext_vector_type(4)));
typedef short bf16x8 __attribute__((ext_vector_type(8)));

#define MFMA16(a, b, c) __builtin_amdgcn_mfma_f32_16x16x32_bf16((a), (b), (c), 0, 0, 0)
#define RCPF(x) __builtin_amdgcn_rcpf(x)
#define LOG2E 1.442695041f

// Compiler-generated exp2 (hazard-safe; R3-proven pattern). NO inline-asm VALU
// anywhere in this kernel: R5/R6 failures are attributed to hand-asm
// v_permlane/v_exp missing the wait-states the compiler inserts for its own.
#if __has_builtin(__builtin_amdgcn_exp2f)
#define EXP2(x) __builtin_amdgcn_exp2f(x)
#else
#define EXP2(x) exp2f(x)
#endif

// Per-step barrier: drain LDS, HW barrier, then zero-cost COMPILER memory
// fence so LDS reads can't be hoisted above the barrier. Keeps global
// x-prefetch loads in flight (no vmcnt drain). No sched_barrier (R4: -50us).
#define STEP_SYNC() do {                                  \
    asm volatile("s_waitcnt lgkmcnt(0)" ::: "memory");    \
    __builtin_amdgcn_s_barrier();                         \
    asm volatile("" ::: "memory");                        \
} while (0)

__device__ __forceinline__ short f2bf(float f) {
    unsigned u = __builtin_bit_cast(unsigned, f);
    return (short)((u + 0x7FFFu + ((u >> 16) & 1u)) >> 16);  // RNE
}
__device__ __forceinline__ float bflo(unsigned u) { return __builtin_bit_cast(float, u << 16); }
__device__ __forceinline__ float bfhi(unsigned u) { return __builtin_bit_cast(float, u & 0xFFFF0000u); }
__device__ __forceinline__ float sigm_f(float x) { return RCPF(1.0f + EXP2(x * -LOG2E)); }

// One block per batch element; 512 threads = 8 waves.
// Wave w owns hidden units [16w,16w+16). Gate-split across l4 (i,f,g,o):
// lane (l4,l15) computes only gate l4 for unit l15 via the unified chain
//   t = a*rcp(1+exp2(m*z)) + b ; gates rejoin via 3 parallel shfl (R4-proven).
__launch_bounds__(512, 2)
__global__ void lstm_fused(const float* __restrict__ x, const float* __restrict__ Wx,
                           const float* __restrict__ Wh, const float* __restrict__ bias,
                           const float* __restrict__ Wd, const float* __restrict__ bd,
                           float* __restrict__ out) {
    const int tid = threadIdx.x;
    const int lane = tid & 63;
    const int wid = tid >> 6;      // 0..7
    const int l15 = lane & 15;
    const int l4 = lane >> 4;      // 0..3 == gate (i,f,g,o)
    const int bb = blockIdx.x;

    __shared__ alignas(16) short hist[CH][H_];   // h ring (bf16), slot = t & 15
    __shared__ alignas(16) short xbf[CH][72];    // x chunk (padded)
    __shared__ alignas(16) float xzc[CH][G_];    // layout: [tm][unit*4 + gate]

    ((unsigned*)hist)[tid] = 0u;
    ((unsigned*)hist)[tid + 512] = 0u;

    const int col0 = wid * 16 + l15;             // hidden unit

    // --- Wh B-fragments, col = ct*128 + col0, k = kt*32 + l4*8 + e ---
    bf16x8 bh[4][4];
#pragma unroll
    for (int ct = 0; ct < 4; ++ct) {
        const int col = ct * H_ + col0;
#pragma unroll
        for (int kt = 0; kt < 4; ++kt) {
            bf16x8 v;
#pragma unroll
            for (int e = 0; e < 8; ++e)
                v[e] = f2bf(Wh[(kt * 32 + l4 * 8 + e) * G_ + col]);
            bh[ct][kt] = v;
        }
    }
    // --- Wx B-fragments ---
    bf16x8 bx[4][2];
#pragma unroll
    for (int ct = 0; ct < 4; ++ct) {
        const int col = ct * H_ + col0;
#pragma unroll
        for (int kt = 0; kt < 2; ++kt) {
            bf16x8 v;
#pragma unroll
            for (int e = 0; e < 8; ++e)
                v[e] = f2bf(Wx[(kt * 32 + l4 * 8 + e) * G_ + col]);
            bx[ct][kt] = v;
        }
    }

    float bvr[4];
#pragma unroll
    for (int ct = 0; ct < 4; ++ct) bvr[ct] = bias[ct * H_ + col0];
    const float wd0 = Wd[lane * 2 + 0];
    const float wd1 = Wd[lane * 2 + 1];
    const float bdv = bd[0];
    float c_reg = 0.0f;                          // valid in lanes 0..15 only

    // per-lane unified gate coefficients: t = a*rcp(1+exp2(m*z)) + b
    const float m_c = (l4 == 2) ? (-2.0f * LOG2E) : (-LOG2E);
    const float a_c = (l4 == 2) ? 2.0f : 1.0f;
    const float b_c = (l4 == 2) ? -1.0f : 0.0f;

    const float* xb = x + (size_t)bb * S_ * D_;
    float* ob = out + (size_t)bb * S_;

    float xp0 = xb[tid * 2 + 0];
    float xp1 = xb[tid * 2 + 1];

    // persistent accumulator chains: only reg 0 is meaningful (rows 1-3 stale)
    f32x4 acc0 = {0.f, 0.f, 0.f, 0.f}, acc1 = acc0, acc2 = acc0, acc3 = acc0;

    for (int tc = 0; tc < S_; tc += CH) {
        // commit prefetched x chunk (data dep forces the vmcnt wait here)
        xbf[tid >> 5][(tid & 31) * 2 + 0] = f2bf(xp0);
        xbf[tid >> 5][(tid & 31) * 2 + 1] = f2bf(xp1);
        __syncthreads();
        if (tc + CH < S_) {
            xp0 = xb[(tc + CH) * D_ + tid * 2 + 0];
            xp1 = xb[(tc + CH) * D_ + tid * 2 + 1];
        }
        // xz_chunk = X[16x64] @ Wx + b -> layout [tm][unit*4+gate]
#pragma unroll
        for (int ct = 0; ct < 4; ++ct) {
            f32x4 cacc = {bvr[ct], bvr[ct], bvr[ct], bvr[ct]};
#pragma unroll
            for (int kt = 0; kt < 2; ++kt) {
                const bf16x8 a = *reinterpret_cast<const bf16x8*>(&xbf[l15][kt * 32 + l4 * 8]);
                cacc = MFMA16(a, bx[ct][kt], cacc);
            }
#pragma unroll
            for (int r = 0; r < 4; ++r)
                xzc[l4 * 4 + r][col0 * 4 + ct] = cacc[r];   // D row = (lane>>4)*4+r [m89]
        }
        // dense head for the PREVIOUS chunk (hist = h_{tc-16..tc-1})
        if (tc > 0) {
#pragma unroll
            for (int s = 0; s < 2; ++s) {
                const int row = wid * 2 + s;
                const unsigned hp = *reinterpret_cast<const unsigned*>(&hist[row][lane * 2]);
                float p = bflo(hp) * wd0 + bfhi(hp) * wd1;
                p += __shfl_xor(p, 1);  p += __shfl_xor(p, 2);  p += __shfl_xor(p, 4);
                p += __shfl_xor(p, 8);  p += __shfl_xor(p, 16); p += __shfl_xor(p, 32);
                if (lane == 0) ob[tc - CH + row] = sigm_f(p + bdv);
            }
        }
        __syncthreads();   // xzc ready; hist fully consumed before overwrite

#pragma unroll
        for (int tm = 0; tm < CH; ++tm) {
            const int prev = (tm + CH - 1) & (CH - 1);
            const short* hsrc = hist[prev];
            const bf16x8 a0 = *reinterpret_cast<const bf16x8*>(&hsrc[ 0 + l4 * 8]);
            const bf16x8 a1 = *reinterpret_cast<const bf16x8*>(&hsrc[32 + l4 * 8]);
            const bf16x8 a2 = *reinterpret_cast<const bf16x8*>(&hsrc[64 + l4 * 8]);
            const bf16x8 a3 = *reinterpret_cast<const bf16x8*>(&hsrc[96 + l4 * 8]);
            // this lane's 4 gate pre-activations (i,f,g,o for unit col0), one b128
            const f32x4 xzq = *reinterpret_cast<const f32x4*>(&xzc[tm][col0 * 4]);

            // init only reg 0 of each chain (row l4*4 is the only row read)
            acc0[0] = xzq[0];  acc1[0] = xzq[1];  acc2[0] = xzq[2];  acc3[0] = xzq[3];

            acc0 = MFMA16(a0, bh[0][0], acc0);
            acc1 = MFMA16(a0, bh[1][0], acc1);
            acc2 = MFMA16(a0, bh[2][0], acc2);
            acc3 = MFMA16(a0, bh[3][0], acc3);
            acc0 = MFMA16(a1, bh[0][1], acc0);
            acc1 = MFMA16(a1, bh[1][1], acc1);
            acc2 = MFMA16(a1, bh[2][1], acc2);
            acc3 = MFMA16(a1, bh[3][1], acc3);
            acc0 = MFMA16(a2, bh[0][2], acc0);
            acc1 = MFMA16(a2, bh[1][2], acc1);
            acc2 = MFMA16(a2, bh[2][2], acc2);
            acc3 = MFMA16(a2, bh[3][2], acc3);
            acc0 = MFMA16(a3, bh[0][3], acc0);
            acc1 = MFMA16(a3, bh[1][3], acc1);
            acc2 = MFMA16(a3, bh[2][3], acc2);
            acc3 = MFMA16(a3, bh[3][3], acc3);

            // lane's gate z (A replicated -> row 0 valid in every lane)
            const bool bb0 = (l4 & 1) != 0, bb1 = (l4 & 2) != 0;
            const float zsel = bb1 ? (bb0 ? acc3[0] : acc2[0]) : (bb0 ? acc1[0] : acc0[0]);

            // unified gate activation (1 exp2 + 1 rcp)
            const float t = __builtin_fmaf(a_c, RCPF(1.0f + EXP2(zsel * m_c)), b_c);

            // rejoin via 3 parallel shfl: group 0 receives f, g, o (R4-proven)
            const float rf = __shfl_xor(t, 16);
            const float r2 = __shfl_xor(t, 32);
            const float ro = __shfl_xor(t, 48);

            if (lane < 16) {
                c_reg = __builtin_fmaf(rf, c_reg, t * r2);   // f*c + i*g
                // h = ro * tanh(c) = fma(2*ro, rcp(1+exp2(-2c*log2e)), -ro)
                const float r = RCPF(1.0f + EXP2(c_reg * (-2.0f * LOG2E)));
                const float hv = __builtin_fmaf(2.0f * ro, r, -ro);
                hist[tm][col0] = f2bf(hv);
            }
            STEP_SYNC();   // h_t visible to all waves for step t+1
        }
    }

    // dense head for the final 16 steps
#pragma unroll
    for (int s = 0; s < 2; ++s) {
        const int row = wid * 2 + s;
        const unsigned hp = *reinterpret_cast<const unsigned*>(&hist[row][lane * 2]);
        float p = bflo(hp) * wd0 + bfhi(hp) * wd1;
        p += __shfl_xor(p, 1);  p += __shfl_xor(p, 2);  p += __shfl_xor(p, 4);
        p += __shfl_xor(p, 8);  p += __shfl_xor(p, 16); p += __shfl_xor(p, 32);
        if (lane == 0) ob[S_ - CH + row] = sigm_f(p + bdv);
    }
}

extern "C" void kernel_launch(void* const* d_in, const int* in_sizes, int n_in,
                              void* d_out, int out_size, void* d_ws, size_t ws_size,
                              hipStream_t stream) {
    const float* x  = (const float*)d_in[0];
    const float* Wx = (const float*)d_in[1];
    const float* Wh = (const float*)d_in[2];
    const float* b  = (const float*)d_in[3];
    const float* Wd = (const float*)d_in[4];
    const float* bd = (const float*)d_in[5];
    float* out = (float*)d_out;

    lstm_fused<<<B_, 512, 0, stream>>>(x, Wx, Wh, b, Wd, bd, out);
}

// Round 8
// 955.546 us; speedup vs baseline: 1.1695x; 1.1382x over previous
//
#include <hip/hip_runtime.h>

#define B_ 64
#define S_ 2048
#define D_ 64
#define H_ 128
#define G_ 512
#define CH 16

typedef float f32x4 __attribute__((ext_vector_type(4)));
typedef short bf16x8 __attribute__((ext_vector_type(8)));

#define MFMA16(a, b, c) __builtin_amdgcn_mfma_f32_16x16x32_bf16((a), (b), (c), 0, 0, 0)
#define RCPF(x) __builtin_amdgcn_rcpf(x)
#define LOG2E 1.442695041f

// Compiler-generated exp2 only (R5/R6 lesson: hand-asm VALU loses the
// compiler's hazard wait-states -> silent corruption).
#if __has_builtin(__builtin_amdgcn_exp2f)
#define EXP2(x) __builtin_amdgcn_exp2f(x)
#else
#define EXP2(x) exp2f(x)
#endif

// Per-step barrier: drain LDS, HW barrier, zero-cost compiler memory fence
// (keeps global x-prefetch in flight; no sched_barrier -> no R4 pinning).
#define STEP_SYNC() do {                                  \
    asm volatile("s_waitcnt lgkmcnt(0)" ::: "memory");    \
    __builtin_amdgcn_s_barrier();                         \
    asm volatile("" ::: "memory");                        \
} while (0)

__device__ __forceinline__ short f2bf(float f) {
    unsigned u = __builtin_bit_cast(unsigned, f);
    return (short)((u + 0x7FFFu + ((u >> 16) & 1u)) >> 16);  // RNE
}
__device__ __forceinline__ float bflo(unsigned u) { return __builtin_bit_cast(float, u << 16); }
__device__ __forceinline__ float bfhi(unsigned u) { return __builtin_bit_cast(float, u & 0xFFFF0000u); }
__device__ __forceinline__ float sigm_f(float x) { return RCPF(1.0f + EXP2(x * -LOG2E)); }
__device__ __forceinline__ float tanh_f(float x) {   // 2*sigm(2x)-1
    return __builtin_fmaf(2.0f, RCPF(1.0f + EXP2(x * (-2.0f * LOG2E))), -1.0f);
}

// One block per batch element; 512 threads = 8 waves.
// Wave w owns hidden units [16w,16w+16). ALL-GATES-PER-LANE: every lane
// computes i,f,g,o for unit l15 directly from its 4 accumulator chains
// (A-operand replicated across M -> reg0 valid in every lane; xz folded in
// via C-init). No cross-lane rejoin on the critical chain (R8 change: the
// R3 gate-split's 3-bpermute hop sat on the serial h-recurrence path).
__launch_bounds__(512, 2)
__global__ void lstm_fused(const float* __restrict__ x, const float* __restrict__ Wx,
                           const float* __restrict__ Wh, const float* __restrict__ bias,
                           const float* __restrict__ Wd, const float* __restrict__ bd,
                           float* __restrict__ out) {
    const int tid = threadIdx.x;
    const int lane = tid & 63;
    const int wid = tid >> 6;      // 0..7
    const int l15 = lane & 15;
    const int l4 = lane >> 4;      // 0..3 (fragment row-group; gate loop is local now)
    const int bb = blockIdx.x;

    __shared__ alignas(16) short hist[CH][H_];   // h ring (bf16), slot = t & 15
    __shared__ alignas(16) short xbf[CH][72];    // x chunk (padded)
    __shared__ alignas(16) float xzc[CH][G_];    // layout: [tm][unit*4 + gate]

    ((unsigned*)hist)[tid] = 0u;
    ((unsigned*)hist)[tid + 512] = 0u;

    const int col0 = wid * 16 + l15;             // hidden unit

    // --- Wh B-fragments, col = gate*128 + col0, k = kt*32 + l4*8 + e ---
    bf16x8 bh[4][4];
#pragma unroll
    for (int ct = 0; ct < 4; ++ct) {
        const int col = ct * H_ + col0;
#pragma unroll
        for (int kt = 0; kt < 4; ++kt) {
            bf16x8 v;
#pragma unroll
            for (int e = 0; e < 8; ++e)
                v[e] = f2bf(Wh[(kt * 32 + l4 * 8 + e) * G_ + col]);
            bh[ct][kt] = v;
        }
    }
    // --- Wx B-fragments ---
    bf16x8 bx[4][2];
#pragma unroll
    for (int ct = 0; ct < 4; ++ct) {
        const int col = ct * H_ + col0;
#pragma unroll
        for (int kt = 0; kt < 2; ++kt) {
            bf16x8 v;
#pragma unroll
            for (int e = 0; e < 8; ++e)
                v[e] = f2bf(Wx[(kt * 32 + l4 * 8 + e) * G_ + col]);
            bx[ct][kt] = v;
        }
    }

    float bvr[4];
#pragma unroll
    for (int ct = 0; ct < 4; ++ct) bvr[ct] = bias[ct * H_ + col0];
    const float wd0 = Wd[lane * 2 + 0];
    const float wd1 = Wd[lane * 2 + 1];
    const float bdv = bd[0];
    float c_reg = 0.0f;    // replicated consistently in ALL lanes (no divergence)

    const float* xb = x + (size_t)bb * S_ * D_;
    float* ob = out + (size_t)bb * S_;

    float xp0 = xb[tid * 2 + 0];
    float xp1 = xb[tid * 2 + 1];

    // persistent accumulator chains: only reg 0 is meaningful (rows 1-3 stale)
    f32x4 acc0 = {0.f, 0.f, 0.f, 0.f}, acc1 = acc0, acc2 = acc0, acc3 = acc0;

    for (int tc = 0; tc < S_; tc += CH) {
        // commit prefetched x chunk (data dep forces the vmcnt wait here)
        xbf[tid >> 5][(tid & 31) * 2 + 0] = f2bf(xp0);
        xbf[tid >> 5][(tid & 31) * 2 + 1] = f2bf(xp1);
        __syncthreads();
        if (tc + CH < S_) {
            xp0 = xb[(tc + CH) * D_ + tid * 2 + 0];
            xp1 = xb[(tc + CH) * D_ + tid * 2 + 1];
        }
        // xz_chunk = X[16x64] @ Wx + b -> layout [tm][unit*4+gate]
#pragma unroll
        for (int ct = 0; ct < 4; ++ct) {
            f32x4 cacc = {bvr[ct], bvr[ct], bvr[ct], bvr[ct]};
#pragma unroll
            for (int kt = 0; kt < 2; ++kt) {
                const bf16x8 a = *reinterpret_cast<const bf16x8*>(&xbf[l15][kt * 32 + l4 * 8]);
                cacc = MFMA16(a, bx[ct][kt], cacc);
            }
#pragma unroll
            for (int r = 0; r < 4; ++r)
                xzc[l4 * 4 + r][col0 * 4 + ct] = cacc[r];   // D row = (lane>>4)*4+r [m89]
        }
        // dense head for the PREVIOUS chunk (hist = h_{tc-16..tc-1})
        if (tc > 0) {
#pragma unroll
            for (int s = 0; s < 2; ++s) {
                const int row = wid * 2 + s;
                const unsigned hp = *reinterpret_cast<const unsigned*>(&hist[row][lane * 2]);
                float p = bflo(hp) * wd0 + bfhi(hp) * wd1;
                p += __shfl_xor(p, 1);  p += __shfl_xor(p, 2);  p += __shfl_xor(p, 4);
                p += __shfl_xor(p, 8);  p += __shfl_xor(p, 16); p += __shfl_xor(p, 32);
                if (lane == 0) ob[tc - CH + row] = sigm_f(p + bdv);
            }
        }
        __syncthreads();   // xzc ready; hist fully consumed before overwrite

#pragma unroll
        for (int tm = 0; tm < CH; ++tm) {
            const int prev = (tm + CH - 1) & (CH - 1);
            const short* hsrc = hist[prev];
            const bf16x8 a0 = *reinterpret_cast<const bf16x8*>(&hsrc[ 0 + l4 * 8]);
            const bf16x8 a1 = *reinterpret_cast<const bf16x8*>(&hsrc[32 + l4 * 8]);
            const bf16x8 a2 = *reinterpret_cast<const bf16x8*>(&hsrc[64 + l4 * 8]);
            const bf16x8 a3 = *reinterpret_cast<const bf16x8*>(&hsrc[96 + l4 * 8]);
            // this lane's 4 gate pre-activations (i,f,g,o for unit col0), one b128
            const f32x4 xzq = *reinterpret_cast<const f32x4*>(&xzc[tm][col0 * 4]);

            // init only reg 0 of each chain (row l4*4 is the only row read)
            acc0[0] = xzq[0];  acc1[0] = xzq[1];  acc2[0] = xzq[2];  acc3[0] = xzq[3];

            acc0 = MFMA16(a0, bh[0][0], acc0);
            acc1 = MFMA16(a0, bh[1][0], acc1);
            acc2 = MFMA16(a0, bh[2][0], acc2);
            acc3 = MFMA16(a0, bh[3][0], acc3);
            acc0 = MFMA16(a1, bh[0][1], acc0);
            acc1 = MFMA16(a1, bh[1][1], acc1);
            acc2 = MFMA16(a1, bh[2][1], acc2);
            acc3 = MFMA16(a1, bh[3][1], acc3);
            acc0 = MFMA16(a2, bh[0][2], acc0);
            acc1 = MFMA16(a2, bh[1][2], acc1);
            acc2 = MFMA16(a2, bh[2][2], acc2);
            acc3 = MFMA16(a2, bh[3][2], acc3);
            acc0 = MFMA16(a3, bh[0][3], acc0);
            acc1 = MFMA16(a3, bh[1][3], acc1);
            acc2 = MFMA16(a3, bh[2][3], acc2);
            acc3 = MFMA16(a3, bh[3][3], acc3);

            // all 4 gates locally (reg 0 valid in every lane; no cross-lane op)
            const float iv = sigm_f(acc0[0]);
            const float fv = sigm_f(acc1[0]);
            const float gv = tanh_f(acc2[0]);
            const float ov = sigm_f(acc3[0]);

            c_reg = __builtin_fmaf(fv, c_reg, iv * gv);   // f*c + i*g
            const float hv = ov * tanh_f(c_reg);

            if (lane < 16) hist[tm][col0] = f2bf(hv);
            STEP_SYNC();   // h_t visible to all waves for step t+1
        }
    }

    // dense head for the final 16 steps
#pragma unroll
    for (int s = 0; s < 2; ++s) {
        const int row = wid * 2 + s;
        const unsigned hp = *reinterpret_cast<const unsigned*>(&hist[row][lane * 2]);
        float p = bflo(hp) * wd0 + bfhi(hp) * wd1;
        p += __shfl_xor(p, 1);  p += __shfl_xor(p, 2);  p += __shfl_xor(p, 4);
        p += __shfl_xor(p, 8);  p += __shfl_xor(p, 16); p += __shfl_xor(p, 32);
        if (lane == 0) ob[S_ - CH + row] = sigm_f(p + bdv);
    }
}

extern "C" void kernel_launch(void* const* d_in, const int* in_sizes, int n_in,
                              void* d_out, int out_size, void* d_ws, size_t ws_size,
                              hipStream_t stream) {
    const float* x  = (const float*)d_in[0];
    const float* Wx = (const float*)d_in[1];
    const float* Wh = (const float*)d_in[2];
    const float* b  = (const float*)d_in[3];
    const float* Wd = (const float*)d_in[4];
    const float* bd = (const float*)d_in[5];
    float* out = (float*)d_out;

    lstm_fused<<<B_, 512, 0, stream>>>(x, Wx, Wh, b, Wd, bd, out);
}

// Round 9
// 954.424 us; speedup vs baseline: 1.1709x; 1.0012x over previous
//
#include <hip/hip_runtime.h>

#define B_ 64
#define S_ 2048
#define D_ 64
#define H_ 128
#define G_ 512
#define CH 16
#define NCHUNK (S_ / CH)

typedef float f32x4 __attribute__((ext_vector_type(4)));
typedef short bf16x8 __attribute__((ext_vector_type(8)));

#define MFMA16(a, b, c) __builtin_amdgcn_mfma_f32_16x16x32_bf16((a), (b), (c), 0, 0, 0)
#define RCPF(x) __builtin_amdgcn_rcpf(x)
#define LOG2E 1.442695041f

#if __has_builtin(__builtin_amdgcn_exp2f)
#define EXP2(x) __builtin_amdgcn_exp2f(x)
#else
#define EXP2(x) exp2f(x)
#endif

// Per-step barrier: drain LDS, HW barrier, zero-cost compiler memory fence.
// (R7-proven; keeps global prefetch in flight, no scheduler pinning.)
#define STEP_SYNC() do {                                  \
    asm volatile("s_waitcnt lgkmcnt(0)" ::: "memory");    \
    __builtin_amdgcn_s_barrier();                         \
    asm volatile("" ::: "memory");                        \
} while (0)

__device__ __forceinline__ short f2bf(float f) {
    unsigned u = __builtin_bit_cast(unsigned, f);
    return (short)((u + 0x7FFFu + ((u >> 16) & 1u)) >> 16);  // RNE
}
__device__ __forceinline__ float bflo(unsigned u) { return __builtin_bit_cast(float, u << 16); }
__device__ __forceinline__ float bfhi(unsigned u) { return __builtin_bit_cast(float, u & 0xFFFF0000u); }
__device__ __forceinline__ float sigm_f(float x) { return RCPF(1.0f + EXP2(x * -LOG2E)); }

// One block per batch element; 512 threads = 8 waves. Wave w owns hidden
// units [16w,16w+16); all-gates-per-lane (R8). Weights prescaled by
// -log2e (-2log2e for g) so gate chains feed exp2 directly.
// Chunk-boundary work (x commit, next-chunk xz GEMM, dense head) is
// pipelined into the 16 steps; h ring is double-buffered by chunk parity so
// the head reads a stable buffer.
__launch_bounds__(512, 2)
__global__ void lstm_fused(const float* __restrict__ x, const float* __restrict__ Wx,
                           const float* __restrict__ Wh, const float* __restrict__ bias,
                           const float* __restrict__ Wd, const float* __restrict__ bd,
                           float* __restrict__ out) {
    const int tid = threadIdx.x;
    const int lane = tid & 63;
    const int wid = tid >> 6;      // 0..7
    const int l15 = lane & 15;
    const int l4 = lane >> 4;      // 0..3
    const int bb = blockIdx.x;

    __shared__ alignas(16) short hbuf[2][CH][H_];   // h ring, dbuf by chunk parity (8KB)
    __shared__ alignas(16) short xbf[CH][72];       // x chunk (padded)
    __shared__ alignas(16) float xzc[2][CH][G_];    // xz dbuf: [buf][tm][unit*4+gate] (64KB)

    // zero hbuf (2048 dwords / 512 threads)
    {
        unsigned* hz = (unsigned*)hbuf;
        hz[tid] = 0u; hz[tid + 512] = 0u; hz[tid + 1024] = 0u; hz[tid + 1536] = 0u;
    }

    const int col0 = wid * 16 + l15;             // hidden unit

    // --- prescaled Wh B-fragments, col = gate*128 + col0, k = kt*32+l4*8+e ---
    bf16x8 bh[4][4];
#pragma unroll
    for (int ct = 0; ct < 4; ++ct) {
        const float msc = (ct == 2) ? (-2.0f * LOG2E) : (-LOG2E);
        const int col = ct * H_ + col0;
#pragma unroll
        for (int kt = 0; kt < 4; ++kt) {
            bf16x8 v;
#pragma unroll
            for (int e = 0; e < 8; ++e)
                v[e] = f2bf(Wh[(kt * 32 + l4 * 8 + e) * G_ + col] * msc);
            bh[ct][kt] = v;
        }
    }
    // --- prescaled Wx B-fragments ---
    bf16x8 bx[4][2];
#pragma unroll
    for (int ct = 0; ct < 4; ++ct) {
        const float msc = (ct == 2) ? (-2.0f * LOG2E) : (-LOG2E);
        const int col = ct * H_ + col0;
#pragma unroll
        for (int kt = 0; kt < 2; ++kt) {
            bf16x8 v;
#pragma unroll
            for (int e = 0; e < 8; ++e)
                v[e] = f2bf(Wx[(kt * 32 + l4 * 8 + e) * G_ + col] * msc);
            bx[ct][kt] = v;
        }
    }

    float bvr[4];
#pragma unroll
    for (int ct = 0; ct < 4; ++ct)
        bvr[ct] = bias[ct * H_ + col0] * ((ct == 2) ? (-2.0f * LOG2E) : (-LOG2E));
    const float wd0 = Wd[lane * 2 + 0];
    const float wd1 = Wd[lane * 2 + 1];
    const float bdv = bd[0];
    float c_reg = 0.0f;

    const float* xb = x + (size_t)bb * S_ * D_;
    float* ob = out + (size_t)bb * S_;

    float xp0, xp1;

    // ---- prologue: stage + GEMM chunk 0, prefetch chunk 1 ----
    {
        const float a0v = xb[tid * 2 + 0];
        const float a1v = xb[tid * 2 + 1];
        const unsigned pk = ((unsigned)(unsigned short)f2bf(a0v)) |
                            (((unsigned)(unsigned short)f2bf(a1v)) << 16);
        *reinterpret_cast<unsigned*>(&xbf[tid >> 5][(tid & 31) * 2]) = pk;
        __syncthreads();
        xp0 = xb[CH * D_ + tid * 2 + 0];
        xp1 = xb[CH * D_ + tid * 2 + 1];
#pragma unroll
        for (int ct = 0; ct < 4; ++ct) {
            f32x4 cc = {bvr[ct], bvr[ct], bvr[ct], bvr[ct]};
#pragma unroll
            for (int kt = 0; kt < 2; ++kt) {
                const bf16x8 a = *reinterpret_cast<const bf16x8*>(&xbf[l15][kt * 32 + l4 * 8]);
                cc = MFMA16(a, bx[ct][kt], cc);
            }
#pragma unroll
            for (int r = 0; r < 4; ++r)
                xzc[0][l4 * 4 + r][col0 * 4 + ct] = cc[r];   // D row = (lane>>4)*4+r [m89]
        }
        __syncthreads();
    }

    // persistent accumulator chains: only reg 0 meaningful (rows 1-3 stale)
    f32x4 acc0 = {0.f, 0.f, 0.f, 0.f}, acc1 = acc0, acc2 = acc0, acc3 = acc0;
    bf16x8 gf0, gf1;   // staged A-frags for the pipelined xz GEMM

    for (int k = 0; k < NCHUNK; ++k) {
        const int cur = k & 1, prv = cur ^ 1;
        const bool notlast = (k < NCHUNK - 1);

#pragma unroll
        for (int tm = 0; tm < CH; ++tm) {
            // ---- recurrent step ----
            const short* hsrc = (tm == 0) ? hbuf[prv][CH - 1] : hbuf[cur][tm - 1];
            const bf16x8 a0 = *reinterpret_cast<const bf16x8*>(&hsrc[ 0 + l4 * 8]);
            const bf16x8 a1 = *reinterpret_cast<const bf16x8*>(&hsrc[32 + l4 * 8]);
            const bf16x8 a2 = *reinterpret_cast<const bf16x8*>(&hsrc[64 + l4 * 8]);
            const bf16x8 a3 = *reinterpret_cast<const bf16x8*>(&hsrc[96 + l4 * 8]);
            const f32x4 xzq = *reinterpret_cast<const f32x4*>(&xzc[cur][tm][col0 * 4]);

            acc0[0] = xzq[0];  acc1[0] = xzq[1];  acc2[0] = xzq[2];  acc3[0] = xzq[3];

            acc0 = MFMA16(a0, bh[0][0], acc0);
            acc1 = MFMA16(a0, bh[1][0], acc1);
            acc2 = MFMA16(a0, bh[2][0], acc2);
            acc3 = MFMA16(a0, bh[3][0], acc3);
            acc0 = MFMA16(a1, bh[0][1], acc0);
            acc1 = MFMA16(a1, bh[1][1], acc1);
            acc2 = MFMA16(a1, bh[2][1], acc2);
            acc3 = MFMA16(a1, bh[3][1], acc3);
            acc0 = MFMA16(a2, bh[0][2], acc0);
            acc1 = MFMA16(a2, bh[1][2], acc1);
            acc2 = MFMA16(a2, bh[2][2], acc2);
            acc3 = MFMA16(a2, bh[3][2], acc3);
            acc0 = MFMA16(a3, bh[0][3], acc0);
            acc1 = MFMA16(a3, bh[1][3], acc1);
            acc2 = MFMA16(a3, bh[2][3], acc2);
            acc3 = MFMA16(a3, bh[3][3], acc3);

            // gates: prescaled z feeds exp2 directly
            const float iv = RCPF(1.0f + EXP2(acc0[0]));
            const float fv = RCPF(1.0f + EXP2(acc1[0]));
            const float gv = __builtin_fmaf(2.0f, RCPF(1.0f + EXP2(acc2[0])), -1.0f);
            const float ov = RCPF(1.0f + EXP2(acc3[0]));

            c_reg = __builtin_fmaf(fv, c_reg, iv * gv);
            const float th = __builtin_fmaf(
                2.0f, RCPF(1.0f + EXP2(c_reg * (-2.0f * LOG2E))), -1.0f);
            const float hv = ov * th;

            if (lane < 16) hbuf[cur][tm][col0] = f2bf(hv);

            // ---- pipelined boundary work (compile-time tm dispatch) ----
            if (tm == 0 && notlast) {
                // commit chunk k+1's x (prefetched) to xbf; prefetch chunk k+2
                const unsigned pk = ((unsigned)(unsigned short)f2bf(xp0)) |
                                    (((unsigned)(unsigned short)f2bf(xp1)) << 16);
                *reinterpret_cast<unsigned*>(&xbf[tid >> 5][(tid & 31) * 2]) = pk;
                if (k < NCHUNK - 2) {
                    xp0 = xb[(k + 2) * CH * D_ + tid * 2 + 0];
                    xp1 = xb[(k + 2) * CH * D_ + tid * 2 + 1];
                }
            }
            if (tm == 1 && notlast)
                gf0 = *reinterpret_cast<const bf16x8*>(&xbf[l15][ 0 + l4 * 8]);
            if (tm == 3 && notlast)
                gf1 = *reinterpret_cast<const bf16x8*>(&xbf[l15][32 + l4 * 8]);
            if ((tm == 4 || tm == 6 || tm == 8 || tm == 10) && notlast) {
                const int ct = (tm - 4) >> 1;
                f32x4 cc = {bvr[ct], bvr[ct], bvr[ct], bvr[ct]};
                cc = MFMA16(gf0, bx[ct][0], cc);
                cc = MFMA16(gf1, bx[ct][1], cc);
#pragma unroll
                for (int r = 0; r < 4; ++r)
                    xzc[prv][l4 * 4 + r][col0 * 4 + ct] = cc[r];
            }
            if ((tm == 5 || tm == 13) && k > 0) {
                // dense head for chunk k-1 (stable buffer hbuf[prv])
                const int row = wid * 2 + (tm == 13 ? 1 : 0);
                const unsigned hp =
                    *reinterpret_cast<const unsigned*>(&hbuf[prv][row][lane * 2]);
                float p = bflo(hp) * wd0 + bfhi(hp) * wd1;
                p += __shfl_xor(p, 1);  p += __shfl_xor(p, 2);  p += __shfl_xor(p, 4);
                p += __shfl_xor(p, 8);  p += __shfl_xor(p, 16); p += __shfl_xor(p, 32);
                if (lane == 0) ob[(k - 1) * CH + row] = sigm_f(p + bdv);
            }

            STEP_SYNC();   // h_t (and staged LDS) visible to all waves
        }
    }

    // dense head for the final chunk (chunk 127 lives in hbuf[1])
#pragma unroll
    for (int s = 0; s < 2; ++s) {
        const int row = wid * 2 + s;
        const unsigned hp = *reinterpret_cast<const unsigned*>(&hbuf[1][row][lane * 2]);
        float p = bflo(hp) * wd0 + bfhi(hp) * wd1;
        p += __shfl_xor(p, 1);  p += __shfl_xor(p, 2);  p += __shfl_xor(p, 4);
        p += __shfl_xor(p, 8);  p += __shfl_xor(p, 16); p += __shfl_xor(p, 32);
        if (lane == 0) ob[S_ - CH + row] = sigm_f(p + bdv);
    }
}

extern "C" void kernel_launch(void* const* d_in, const int* in_sizes, int n_in,
                              void* d_out, int out_size, void* d_ws, size_t ws_size,
                              hipStream_t stream) {
    const float* x  = (const float*)d_in[0];
    const float* Wx = (const float*)d_in[1];
    const float* Wh = (const float*)d_in[2];
    const float* b  = (const float*)d_in[3];
    const float* Wd = (const float*)d_in[4];
    const float* bd = (const float*)d_in[5];
    float* out = (float*)d_out;

    lstm_fused<<<B_, 512, 0, stream>>>(x, Wx, Wh, b, Wd, bd, out);
}